// Round 14
// baseline (854.738 us; speedup 1.0000x reference)
//
#include <hip/hip_runtime.h>
#include <hip/hip_bf16.h>

#define TOKENS 2048
#define HDIM   2560
#define NEXP   16
#define IDIM   1664
#define ISDIM  3328
#define NPAIR  (TOKENS*2)
#define NPERS  768    // persistent blocks (3/CU x 256)
#define CONVN  18720  // dn-phase conv tiles: w2 16*20*52=16640 + sd 20*104=2080

typedef float  f32x4   __attribute__((ext_vector_type(4)));
typedef __bf16 bf16x8  __attribute__((ext_vector_type(8)));
typedef short  short8v __attribute__((ext_vector_type(8)));

#define GLDS16(g, l) __builtin_amdgcn_global_load_lds( \
    (const __attribute__((address_space(1))) unsigned int*)(g), \
    (__attribute__((address_space(3))) unsigned int*)(l), 16, 0, 0)

#define VMCNT(n) asm volatile("s_waitcnt vmcnt(" #n ")" ::: "memory")
#define LGKM_BAR() do { \
    asm volatile("s_waitcnt lgkmcnt(0)" ::: "memory"); \
    __builtin_amdgcn_sched_barrier(0); \
    __builtin_amdgcn_s_barrier(); \
    __builtin_amdgcn_sched_barrier(0); \
  } while (0)

__device__ __forceinline__ short f2bf(float f) {
  unsigned u = __builtin_bit_cast(unsigned, f);
  u += 0x7FFFu + ((u >> 16) & 1u);          // RNE to bf16
  return (short)(u >> 16);
}

// ---- shared conv-tile: 32k x BN fp32 (N-contig rows) -> bf16 tile-linear,
// pre-swizzled (unit u = n*4 + (koct ^ ((n>>1)&3)), byte j = k&7).
// Fully-coalesced global read AND write; transpose via LDS (stride BN+4).
template <int BN>
__device__ __forceinline__ void conv_tile(const float* __restrict__ src,
                                          short* __restrict__ dst,
                                          const int N, const int tid,
                                          float* __restrict__ lds) {
  const int FPT = BN / 8;                    // floats per thread (8 or 16)
#pragma unroll
  for (int c4 = 0; c4 < FPT / 4; ++c4) {
    const int f = tid * FPT + c4 * 4;
    const int row = f / BN, col = f % BN;
    f32x4 v = *reinterpret_cast<const f32x4*>(src + (size_t)row * N + col);
    *reinterpret_cast<f32x4*>(lds + row * (BN + 4) + col) = v;
  }
  __syncthreads();
#pragma unroll
  for (int q = 0; q < BN / 64; ++q) {
    const int uidx = tid + q * 256;
    const int n = uidx >> 2, u = uidx & 3;
    const int koct = u ^ ((n >> 1) & 3);
    short8v o;
#pragma unroll
    for (int j = 0; j < 8; ++j) o[j] = f2bf(lds[(koct * 8 + j) * (BN + 4) + n]);
    *reinterpret_cast<short8v*>(dst + uidx * 8) = o;
  }
  __syncthreads();
}

// ---------------- router: fp32 logits, softmax-top2-renorm == sigmoid(l0-l1)
__global__ void router_kernel(const float* __restrict__ x, const float* __restrict__ rw,
                              int* __restrict__ counts, int* __restrict__ tidx,
                              float* __restrict__ tw) {
  const int t = blockIdx.x;
  const int lane = threadIdx.x;
  float acc[NEXP];
#pragma unroll
  for (int e = 0; e < NEXP; ++e) acc[e] = 0.f;
  const float* xr = x + (size_t)t * HDIM;
  for (int k = lane; k < HDIM; k += 64) {
    float xv = xr[k];
#pragma unroll
    for (int e = 0; e < NEXP; ++e) acc[e] += xv * rw[e * HDIM + k];
  }
#pragma unroll
  for (int e = 0; e < NEXP; ++e) {
#pragma unroll
    for (int o = 32; o > 0; o >>= 1) acc[e] += __shfl_down(acc[e], o);
  }
  if (lane == 0) {
    int i0 = 0; float v0 = acc[0];
#pragma unroll
    for (int e = 1; e < NEXP; ++e) if (acc[e] > v0) { v0 = acc[e]; i0 = e; }
    int i1 = -1; float v1 = -3.4e38f;
#pragma unroll
    for (int e = 0; e < NEXP; ++e) if (e != i0 && acc[e] > v1) { v1 = acc[e]; i1 = e; }
    float w0 = 1.f / (1.f + expf(v1 - v0));
    tidx[t * 2] = i0; tidx[t * 2 + 1] = i1;
    tw[t * 2] = w0;   tw[t * 2 + 1] = 1.f - w0;
    atomicAdd(&counts[i0], 1);
    atomicAdd(&counts[i1], 1);
  }
}

// scan + tile-queue metadata: meta[0..15]=panel prefix, meta[16]=total panels
__global__ void scan_kernel(const int* __restrict__ counts, int* __restrict__ offsets,
                            int* __restrict__ meta) {
  if (threadIdx.x == 0) {
    int a = 0, p = 0;
    for (int e = 0; e < NEXP; ++e) {
      offsets[e] = a;
      meta[e] = p;
      a += counts[e];
      p += (counts[e] + 127) >> 7;     // ceil(cnt/128) panels
    }
    meta[16] = p;
  }
}

// ---------------- bucket pairs + gather bf16 activations
__global__ void gather_kernel(const float* __restrict__ x, const int* __restrict__ tidx,
                              const float* __restrict__ tw, const int* __restrict__ offsets,
                              int* __restrict__ slotc, int* __restrict__ pairpos,
                              float* __restrict__ wrow, short* __restrict__ xb,
                              short* __restrict__ xg) {
  const int t = blockIdx.x, tid = threadIdx.x;
  __shared__ int grs[2];
  if (tid < 2) {
    int e = tidx[t * 2 + tid];
    int slot = atomicAdd(&slotc[e], 1);
    int g = offsets[e] + slot;
    grs[tid] = g;
    pairpos[t * 2 + tid] = g;
    wrow[g] = tw[t * 2 + tid];
  }
  __syncthreads();
  const int g0 = grs[0], g1 = grs[1];
  const float* xr = x + (size_t)t * HDIM;
#pragma unroll
  for (int i = 0; i < HDIM / 256; ++i) {
    int k = tid + i * 256;
    short v = f2bf(xr[k]);
    xb[(size_t)t * HDIM + k] = v;
    xg[(size_t)g0 * HDIM + k] = v;
    xg[(size_t)g1 * HDIM + k] = v;
  }
}

// ---------------- standalone coalesced weight convert (one tile per block)
template <int BN>
__global__ void wconv2_kernel(const float* __restrict__ src, short* __restrict__ dst,
                              const int K, const int N, const int nT, const int kT) {
  __shared__ float lds[32 * (BN + 4)];
  int b = blockIdx.x;
  const int kt = b % kT;
  b /= kT;
  const int nt = b % nT;
  const int slab = b / nT;
  const float* s = src + (size_t)slab * K * N + (size_t)(kt * 32) * N + nt * BN;
  short* d = dst + ((size_t)((slab * nT + nt) * kT + kt)) * BN * 32;
  conv_tile<BN>(s, d, N, threadIdx.x, lds);
}

// ================= merged UP (persistent, 256 thr = 4 waves):
// H = bf16( silu(A*B1) * (A*B3) ).  Block tile 128m x 64n x {G,U}.
// Single-barrier depth-3 K-loop (R13 structure, unchanged).
// dn-phase conversion tiles (w2, sd) Bresenham-interleaved into ticket space.
__launch_bounds__(256, 3)
__global__ void moe_up_k(const short* __restrict__ xg, const short* __restrict__ xb,
                         const short* __restrict__ cw1, const short* __restrict__ cw3,
                         const short* __restrict__ csg, const short* __restrict__ csu,
                         short* __restrict__ hbE, short* __restrict__ hbS,
                         const int* __restrict__ counts, const int* __restrict__ offsets,
                         const int* __restrict__ meta,
                         const float* __restrict__ w2f, const float* __restrict__ sdf,
                         short* __restrict__ cw2d, short* __restrict__ csdd,
                         const int doconv) {
  const int tid = threadIdx.x;
  __shared__ int spre[17];
  __shared__ __align__(16) char pool[49152];
  short (*Ab)[128][32] = (short(*)[128][32])pool;             // [3][128][32]  24KB
  short (*Bb)[128][32] = (short(*)[128][32])(pool + 24576);   // [3][G64|U64][32] 24KB
  float* scratch = (float*)pool;                              // epilogue / conv LDS

  if (tid < 17) spre[tid] = meta[tid];
  __syncthreads();
  const int gemmE = spre[16] * 26;
  const int gemmT = gemmE + 832;
  const long long convN = doconv ? CONVN : 0;
  const long long totalT = (long long)gemmT + convN;

  const int lane = tid & 63;
  const int w = tid >> 6;
  const int wmv = (w & 1) * 64;     // m-half
  const int mat = w >> 1;           // 0=G, 1=U
  const int lrow = lane & 15;
  const int lkg = lane >> 4;
  const int a_ko = (tid & 3) << 3;

  for (long long slot = blockIdx.x; slot < totalT; slot += NPERS) {
    int gIdx;
    if (doconv) {
      const long long k1 = slot * convN / totalT;
      const long long k2 = (slot + 1) * convN / totalT;
      if (k2 > k1) {
        // ---- conversion ticket (BN=128 tile of w2 or sd)
        const int cIdx = (int)k1;
        const float* srcT; short* dstT;
        if (cIdx < 16640) {
          const int kt = cIdx % 52;
          const int rest = cIdx / 52;
          const int n = rest % 20, e = rest / 20;
          srcT = w2f + (size_t)e * IDIM * HDIM + (size_t)(kt * 32) * HDIM + n * 128;
          dstT = cw2d + ((size_t)((e * 20 + n) * 52 + kt)) * 4096;
        } else {
          const int c2 = cIdx - 16640;
          const int kt = c2 % 104;
          const int n = c2 / 104;
          srcT = sdf + (size_t)(kt * 32) * HDIM + n * 128;
          dstT = csdd + ((size_t)(n * 104 + kt)) * 4096;
        }
        conv_tile<128>(srcT, dstT, HDIM, tid, scratch);
        continue;
      }
      gIdx = (int)(slot - k1);
    } else {
      gIdx = (int)slot;
    }

    // ---- GEMM ticket
    const short* A; const short* b1tile; const short* b3tile; short* H;
    int N, mtile, ntile, rowbase = 0, cnt = 0x7fffffff;
    bool expert;
    if (gIdx < gemmE) {
      const int p = gIdx / 26;
      const int n = gIdx % 26;
      int e = 0;
#pragma unroll
      for (int i = 1; i < 16; ++i) if (p >= spre[i]) e = i;
      const int m = p - spre[e];
      cnt = counts[e];
      rowbase = offsets[e];
      mtile = m * 128;
      A = xg;
      b1tile = cw1 + ((size_t)((e * 26 + n) * 80)) * 2048;
      b3tile = cw3 + ((size_t)((e * 26 + n) * 80)) * 2048;
      H = hbE; N = IDIM; ntile = n * 64; expert = true;
    } else {
      const int s = gIdx - gemmE;     // 0..831
      const int n = s % 52;
      const int m = s / 52;           // 0..15
      mtile = m * 128;
      A = xb;
      b1tile = csg + ((size_t)(n * 80)) * 2048;
      b3tile = csu + ((size_t)(n * 80)) * 2048;
      H = hbS; N = ISDIM; ntile = n * 64; expert = false;
    }
    const int K = HDIM;
    const int KT = HDIM / 32;         // 80

    f32x4 acc[4][4];
#pragma unroll
    for (int i = 0; i < 4; ++i)
#pragma unroll
      for (int j = 0; j < 4; ++j) { f32x4 z = {0.f,0.f,0.f,0.f}; acc[i][j] = z; }

    int gr0, gr1;
    {
      int r0 = tid >> 2, r1 = (tid >> 2) + 64;
      gr0 = expert ? (rowbase + mtile + r0) : (mtile + r0);
      gr1 = expert ? (rowbase + mtile + r1) : (mtile + r1);
      if (gr0 > NPAIR - 1) gr0 = NPAIR - 1;
      if (gr1 > NPAIR - 1) gr1 = NPAIR - 1;
    }
    const short* a_src0 = A + (size_t)gr0 * K + a_ko;
    const short* a_src1 = A + (size_t)gr1 * K + a_ko;

#define STAGE_U(kt, buf) do { \
    GLDS16(a_src0 + ((kt) << 5), (short*)Ab[buf] + tid * 8); \
    GLDS16(a_src1 + ((kt) << 5), (short*)Ab[buf] + (tid + 256) * 8); \
    GLDS16(b1tile + (size_t)(kt) * 2048 + tid * 8, (short*)Bb[buf] + tid * 8); \
    GLDS16(b3tile + (size_t)(kt) * 2048 + tid * 8, (short*)Bb[buf] + 2048 + tid * 8); \
  } while (0)

    auto compute = [&](int buf) {
      bf16x8 af[4], bfv[4];
#pragma unroll
      for (int mf = 0; mf < 4; ++mf)
        af[mf] = *reinterpret_cast<const bf16x8*>(&Ab[buf][wmv + mf * 16 + lrow][lkg << 3]);
#pragma unroll
      for (int nf = 0; nf < 4; ++nf) {
        const int nloc = nf * 16 + lrow;
        const int kg = (lkg ^ ((nloc >> 1) & 3)) << 3;
        bfv[nf] = *reinterpret_cast<const bf16x8*>(&Bb[buf][mat * 64 + nloc][kg]);
      }
#pragma unroll
      for (int mf = 0; mf < 4; ++mf)
#pragma unroll
        for (int nf = 0; nf < 4; ++nf)
          acc[mf][nf] = __builtin_amdgcn_mfma_f32_16x16x32_bf16(af[mf], bfv[nf], acc[mf][nf], 0, 0, 0);
    };

    // single-barrier pipelined K-loop (depth-3, stage 2 ahead)
    STAGE_U(0, 0); STAGE_U(1, 1);
    for (int i = 0; i < KT; ++i) {
      if (i + 1 < KT) { VMCNT(4); } else { VMCNT(0); }
      LGKM_BAR();
      if (i + 2 < KT) {
        const int fb = (i + 2) % 3;
        STAGE_U(i + 2, fb);
      }
      compute(i % 3);
    }
    LGKM_BAR();   // all compute reads done before scratch writes

    // epilogue: U-waves export acc to scratch; G-waves fuse silu(g)*u -> H.
    if (mat) {
      float* sc = scratch + (size_t)(w & 1) * 4096;
#pragma unroll
      for (int mf = 0; mf < 4; ++mf)
#pragma unroll
        for (int r = 0; r < 4; ++r) {
          const int row = mf * 16 + ((lane >> 4) << 2) + r;
#pragma unroll
          for (int nf = 0; nf < 4; ++nf)
            sc[row * 64 + nf * 16 + lrow] = acc[mf][nf][r];
        }
    }
    LGKM_BAR();
    if (!mat) {
      const float* sc = scratch + (size_t)(w & 1) * 4096;
#pragma unroll
      for (int mf = 0; mf < 4; ++mf) {
#pragma unroll
        for (int r = 0; r < 4; ++r) {
          const int row = mf * 16 + ((lane >> 4) << 2) + r;
          const int rt = wmv + row;
          if (expert && mtile + rt >= cnt) continue;
          const size_t grow = (size_t)((expert ? rowbase : 0) + mtile + rt);
          const int colb = ntile + lrow;
#pragma unroll
          for (int nf = 0; nf < 4; ++nf) {
            float g = acc[mf][nf][r];
            float u = sc[row * 64 + nf * 16 + lrow];
            H[grow * N + colb + nf * 16] = f2bf(g / (1.f + expf(-g)) * u);
          }
        }
      }
    }
    LGKM_BAR();   // scratch reads complete before next ticket's staging
#undef STAGE_U
  }
}

// ================= merged DOWN (persistent, 256 thr = 4 waves): Out = A*B.
// Block tile 128m x 128n; wave tile 64x64.  Single-barrier K-loop.
// Shared tiles (KT=104) ticketed FIRST so long tiles never start in the tail.
__launch_bounds__(256, 3)
__global__ void moe_dn_k(const short* __restrict__ hbE, const short* __restrict__ hbS,
                         const short* __restrict__ cw2, const short* __restrict__ csd,
                         float* __restrict__ pairs, float* __restrict__ outb,
                         const int* __restrict__ counts, const int* __restrict__ offsets,
                         const float* __restrict__ wrow, const int* __restrict__ meta) {
  const int tid = threadIdx.x;
  __shared__ int spre[17];
  __shared__ short Ab[3][128][32];   // 24 KB, linear
  __shared__ short Bb[3][128][32];   // 24 KB, swizzled [n][k] tile-linear

  if (tid < 17) spre[tid] = meta[tid];
  __syncthreads();
  const int total = spre[16] * 20 + 320;

  const int lane = tid & 63;
  const int w = tid >> 6;
  const int wm = (w >> 1) * 64;
  const int wn = (w & 1) * 64;
  const int lrow = lane & 15;
  const int lkg = lane >> 4;
  const int a_ko = (tid & 3) << 3;

  for (int ticket = blockIdx.x; ticket < total; ticket += NPERS) {
    const short* A; const short* btile; float* Out;
    int K, KT, mtile, ntile, rowbase = 0, cnt = 0x7fffffff;
    bool expert;
    if (ticket < 320) {               // shared first (long tiles)
      const int n = ticket % 20;
      const int m = ticket / 20;      // 0..15
      mtile = m * 128;
      A = hbS;
      btile = csd + ((size_t)(n * 104)) * 4096;
      Out = outb; K = ISDIM; KT = ISDIM / 32; ntile = n * 128; expert = false; // KT=104
    } else {
      const int te = ticket - 320;
      const int p = te / 20;
      const int n = te % 20;
      int e = 0;
#pragma unroll
      for (int i = 1; i < 16; ++i) if (p >= spre[i]) e = i;
      const int m = p - spre[e];
      cnt = counts[e];
      rowbase = offsets[e];
      mtile = m * 128;
      A = hbE;
      btile = cw2 + ((size_t)((e * 20 + n) * 52)) * 4096;
      Out = pairs; K = IDIM; KT = IDIM / 32; ntile = n * 128; expert = true;   // KT=52
    }

    f32x4 acc[4][4];
#pragma unroll
    for (int i = 0; i < 4; ++i)
#pragma unroll
      for (int j = 0; j < 4; ++j) { f32x4 z = {0.f,0.f,0.f,0.f}; acc[i][j] = z; }

    int gr0, gr1;
    {
      int r0 = tid >> 2, r1 = (tid >> 2) + 64;
      gr0 = expert ? (rowbase + mtile + r0) : (mtile + r0);
      gr1 = expert ? (rowbase + mtile + r1) : (mtile + r1);
      if (gr0 > NPAIR - 1) gr0 = NPAIR - 1;
      if (gr1 > NPAIR - 1) gr1 = NPAIR - 1;
    }
    const short* a_src0 = A + (size_t)gr0 * K + a_ko;
    const short* a_src1 = A + (size_t)gr1 * K + a_ko;

#define STAGE_D(kt, buf) do { \
    GLDS16(a_src0 + ((kt) << 5), (short*)Ab[buf] + tid * 8); \
    GLDS16(a_src1 + ((kt) << 5), (short*)Ab[buf] + (tid + 256) * 8); \
    GLDS16(btile + (size_t)(kt) * 4096 + tid * 8, (short*)Bb[buf] + tid * 8); \
    GLDS16(btile + (size_t)(kt) * 4096 + (tid + 256) * 8, (short*)Bb[buf] + (tid + 256) * 8); \
  } while (0)

    auto compute = [&](int buf) {
      bf16x8 af[4], bfv[4];
#pragma unroll
      for (int mf = 0; mf < 4; ++mf)
        af[mf] = *reinterpret_cast<const bf16x8*>(&Ab[buf][wm + mf * 16 + lrow][lkg << 3]);
#pragma unroll
      for (int nf = 0; nf < 4; ++nf) {
        const int n = wn + nf * 16 + lrow;
        const int kg = (lkg ^ ((n >> 1) & 3)) << 3;
        bfv[nf] = *reinterpret_cast<const bf16x8*>(&Bb[buf][n][kg]);
      }
#pragma unroll
      for (int mf = 0; mf < 4; ++mf)
#pragma unroll
        for (int nf = 0; nf < 4; ++nf)
          acc[mf][nf] = __builtin_amdgcn_mfma_f32_16x16x32_bf16(af[mf], bfv[nf], acc[mf][nf], 0, 0, 0);
    };

    // single-barrier pipelined K-loop (depth-3, stage 2 ahead)
    STAGE_D(0, 0); STAGE_D(1, 1);
    for (int i = 0; i < KT; ++i) {
      if (i + 1 < KT) { VMCNT(4); } else { VMCNT(0); }
      LGKM_BAR();
      if (i + 2 < KT) {
        const int fb = (i + 2) % 3;
        STAGE_D(i + 2, fb);
      }
      compute(i % 3);
    }

#pragma unroll
    for (int mf = 0; mf < 4; ++mf) {
#pragma unroll
      for (int r = 0; r < 4; ++r) {
        const int rt = wm + mf * 16 + ((lane >> 4) << 2) + r;
        const int colb = ntile + wn + lrow;
        if (expert) {
          if (mtile + rt < cnt) {
            const int gr = rowbase + mtile + rt;
            const float sc = wrow[gr];
            float* o = Out + (size_t)gr * HDIM + colb;
#pragma unroll
            for (int nf = 0; nf < 4; ++nf) o[nf * 16] = sc * acc[mf][nf][r];
          }
        } else {
          float* o = Out + (size_t)(mtile + rt) * HDIM + colb;
#pragma unroll
          for (int nf = 0; nf < 4; ++nf) o[nf * 16] = acc[mf][nf][r];
        }
      }
    }
    LGKM_BAR();   // final compute reads complete before next ticket's staging
#undef STAGE_D
  }
}

// ---------------- final combine: out[t] += pairs[g0] + pairs[g1]
__global__ void combine_kernel(float* __restrict__ out, const float* __restrict__ pairs,
                               const int* __restrict__ pairpos) {
  const int t = blockIdx.x;
  const int g0 = pairpos[t * 2], g1 = pairpos[t * 2 + 1];
  const f32x4* p0 = (const f32x4*)(pairs + (size_t)g0 * HDIM);
  const f32x4* p1 = (const f32x4*)(pairs + (size_t)g1 * HDIM);
  f32x4* o = (f32x4*)(out + (size_t)t * HDIM);
  for (int c = threadIdx.x; c < HDIM / 4; c += 256)
    o[c] = o[c] + p0[c] + p1[c];
}

extern "C" void kernel_launch(void* const* d_in, const int* in_sizes, int n_in,
                              void* d_out, int out_size, void* d_ws, size_t ws_size,
                              hipStream_t stream) {
  const float* x  = (const float*)d_in[0];
  const float* rw = (const float*)d_in[1];
  const float* w1 = (const float*)d_in[2];
  const float* w3 = (const float*)d_in[3];
  const float* w2 = (const float*)d_in[4];
  const float* sg = (const float*)d_in[5];
  const float* su = (const float*)d_in[6];
  const float* sd = (const float*)d_in[7];
  float* out = (float*)d_out;
  (void)in_sizes; (void)n_in; (void)out_size;

  char* ws = (char*)d_ws;
  size_t off = 0;
  auto alloc = [&](size_t bytes) -> void* {
    void* p = ws + off;
    off = (off + bytes + 255) & ~(size_t)255;
    return p;
  };
  int*   counts  = (int*)alloc(NEXP * 4);          // @0
  int*   slotc   = (int*)alloc(NEXP * 4);          // @256
  int*   offsets = (int*)alloc(NEXP * 4);
  int*   meta    = (int*)alloc(32 * 4);
  int*   tidx    = (int*)alloc(NPAIR * 4);
  float* tw      = (float*)alloc(NPAIR * 4);
  float* wrowv   = (float*)alloc(NPAIR * 4);
  int*   pairpos = (int*)alloc(NPAIR * 4);
  short* xb      = (short*)alloc((size_t)TOKENS * HDIM * 2);
  short* xg      = (short*)alloc((size_t)NPAIR * HDIM * 2);
  short* hbE     = (short*)alloc((size_t)NPAIR * IDIM * 2);
  short* hbS     = (short*)alloc((size_t)TOKENS * ISDIM * 2);
  float* pairs   = (float*)alloc((size_t)NPAIR * HDIM * 4);
  // converted-weight regions
  short* cwA  = (short*)alloc((size_t)NEXP * HDIM * IDIM * 2);   // w1' (w2' if no fold)
  short* cwB  = (short*)alloc((size_t)NEXP * HDIM * IDIM * 2);   // w3'
  short* cwS1 = (short*)alloc((size_t)HDIM * ISDIM * 2);         // sg' (sd' if no fold)
  short* cwS2 = (short*)alloc((size_t)HDIM * ISDIM * 2);         // su'
  // fold regions (only used if workspace permits)
  short* cw2d = (short*)alloc((size_t)NEXP * IDIM * HDIM * 2);   // +136.3 MB
  short* csdd = (short*)alloc((size_t)ISDIM * HDIM * 2);         // +17.0 MB
  const bool fold = (off <= ws_size);

  hipMemsetAsync(d_ws, 0, 512, stream);  // zero counts + slotc

  router_kernel<<<dim3(TOKENS), dim3(64), 0, stream>>>(x, rw, counts, tidx, tw);
  scan_kernel<<<dim3(1), dim3(64), 0, stream>>>(counts, offsets, meta);
  gather_kernel<<<dim3(TOKENS), dim3(256), 0, stream>>>(x, tidx, tw, offsets, slotc,
                                                        pairpos, wrowv, xb, xg);

  // convert up-phase weights (coalesced LDS-transpose version)
  wconv2_kernel<64><<<dim3(NEXP * 26 * 80), dim3(256), 0, stream>>>(w1, cwA, HDIM, IDIM, 26, 80);
  wconv2_kernel<64><<<dim3(NEXP * 26 * 80), dim3(256), 0, stream>>>(w3, cwB, HDIM, IDIM, 26, 80);
  wconv2_kernel<64><<<dim3(52 * 80), dim3(256), 0, stream>>>(sg, cwS1, HDIM, ISDIM, 52, 80);
  wconv2_kernel<64><<<dim3(52 * 80), dim3(256), 0, stream>>>(su, cwS2, HDIM, ISDIM, 52, 80);

  // merged up: persistent; dn-phase conv tiles interleaved (Bresenham) if fold
  moe_up_k<<<dim3(NPERS), dim3(256), 0, stream>>>(
      xg, xb, cwA, cwB, cwS1, cwS2, hbE, hbS, counts, offsets, meta,
      w2, sd, fold ? cw2d : cwA, fold ? csdd : cwS1, fold ? 1 : 0);

  if (!fold) {
    // fallback: convert down-phase weights into the freed up-phase regions
    wconv2_kernel<128><<<dim3(NEXP * 20 * 52), dim3(256), 0, stream>>>(w2, cwA, IDIM, HDIM, 20, 52);
    wconv2_kernel<128><<<dim3(20 * 104), dim3(256), 0, stream>>>(sd, cwS1, ISDIM, HDIM, 20, 104);
  }

  // merged down: persistent 768 blocks
  moe_dn_k<<<dim3(NPERS), dim3(256), 0, stream>>>(
      hbE, hbS, fold ? cw2d : cwA, fold ? csdd : cwS1,
      pairs, out, counts, offsets, wrowv, meta);

  combine_kernel<<<dim3(TOKENS), dim3(256), 0, stream>>>(out, pairs, pairpos);
}

// Round 15
// 782.596 us; speedup vs baseline: 1.0922x; 1.0922x over previous
//
#include <hip/hip_runtime.h>
#include <hip/hip_bf16.h>

#define TOKENS 2048
#define HDIM   2560
#define NEXP   16
#define IDIM   1664
#define ISDIM  3328
#define NPAIR  (TOKENS*2)
#define NPERS  768    // persistent blocks (3/CU x 256)

typedef float  f32x4   __attribute__((ext_vector_type(4)));
typedef __bf16 bf16x8  __attribute__((ext_vector_type(8)));
typedef short  short8v __attribute__((ext_vector_type(8)));

#define GLDS16(g, l) __builtin_amdgcn_global_load_lds( \
    (const __attribute__((address_space(1))) unsigned int*)(g), \
    (__attribute__((address_space(3))) unsigned int*)(l), 16, 0, 0)

#define VMCNT(n) asm volatile("s_waitcnt vmcnt(" #n ")" ::: "memory")
#define LGKM_BAR() do { \
    asm volatile("s_waitcnt lgkmcnt(0)" ::: "memory"); \
    __builtin_amdgcn_sched_barrier(0); \
    __builtin_amdgcn_s_barrier(); \
    __builtin_amdgcn_sched_barrier(0); \
  } while (0)

__device__ __forceinline__ short f2bf(float f) {
  unsigned u = __builtin_bit_cast(unsigned, f);
  u += 0x7FFFu + ((u >> 16) & 1u);          // RNE to bf16
  return (short)(u >> 16);
}

// ---- coalesced conv-tile: 32k x BN fp32 (N-contig rows) -> bf16 tile-linear,
// pre-swizzled (unit u = n*4 + (koct ^ ((n>>1)&3)), byte j = k&7).
template <int BN>
__device__ __forceinline__ void conv_tile(const float* __restrict__ src,
                                          short* __restrict__ dst,
                                          const int N, const int tid,
                                          float* __restrict__ lds) {
  const int FPT = BN / 8;                    // floats per thread (8 or 16)
#pragma unroll
  for (int c4 = 0; c4 < FPT / 4; ++c4) {
    const int f = tid * FPT + c4 * 4;
    const int row = f / BN, col = f % BN;
    f32x4 v = *reinterpret_cast<const f32x4*>(src + (size_t)row * N + col);
    *reinterpret_cast<f32x4*>(lds + row * (BN + 4) + col) = v;
  }
  __syncthreads();
#pragma unroll
  for (int q = 0; q < BN / 64; ++q) {
    const int uidx = tid + q * 256;
    const int n = uidx >> 2, u = uidx & 3;
    const int koct = u ^ ((n >> 1) & 3);
    short8v o;
#pragma unroll
    for (int j = 0; j < 8; ++j) o[j] = f2bf(lds[(koct * 8 + j) * (BN + 4) + n]);
    *reinterpret_cast<short8v*>(dst + uidx * 8) = o;
  }
  __syncthreads();
}

// ---------------- router: fp32 logits, softmax-top2-renorm == sigmoid(l0-l1)
__global__ void router_kernel(const float* __restrict__ x, const float* __restrict__ rw,
                              int* __restrict__ counts, int* __restrict__ tidx,
                              float* __restrict__ tw) {
  const int t = blockIdx.x;
  const int lane = threadIdx.x;
  float acc[NEXP];
#pragma unroll
  for (int e = 0; e < NEXP; ++e) acc[e] = 0.f;
  const float* xr = x + (size_t)t * HDIM;
  for (int k = lane; k < HDIM; k += 64) {
    float xv = xr[k];
#pragma unroll
    for (int e = 0; e < NEXP; ++e) acc[e] += xv * rw[e * HDIM + k];
  }
#pragma unroll
  for (int e = 0; e < NEXP; ++e) {
#pragma unroll
    for (int o = 32; o > 0; o >>= 1) acc[e] += __shfl_down(acc[e], o);
  }
  if (lane == 0) {
    int i0 = 0; float v0 = acc[0];
#pragma unroll
    for (int e = 1; e < NEXP; ++e) if (acc[e] > v0) { v0 = acc[e]; i0 = e; }
    int i1 = -1; float v1 = -3.4e38f;
#pragma unroll
    for (int e = 0; e < NEXP; ++e) if (e != i0 && acc[e] > v1) { v1 = acc[e]; i1 = e; }
    float w0 = 1.f / (1.f + expf(v1 - v0));
    tidx[t * 2] = i0; tidx[t * 2 + 1] = i1;
    tw[t * 2] = w0;   tw[t * 2 + 1] = 1.f - w0;
    atomicAdd(&counts[i0], 1);
    atomicAdd(&counts[i1], 1);
  }
}

// scan + tile-queue metadata: meta[0..15]=panel prefix, meta[16]=total panels
__global__ void scan_kernel(const int* __restrict__ counts, int* __restrict__ offsets,
                            int* __restrict__ meta) {
  if (threadIdx.x == 0) {
    int a = 0, p = 0;
    for (int e = 0; e < NEXP; ++e) {
      offsets[e] = a;
      meta[e] = p;
      a += counts[e];
      p += (counts[e] + 127) >> 7;     // ceil(cnt/128) panels
    }
    meta[16] = p;
  }
}

// ---------------- bucket pairs + gather bf16 activations
__global__ void gather_kernel(const float* __restrict__ x, const int* __restrict__ tidx,
                              const float* __restrict__ tw, const int* __restrict__ offsets,
                              int* __restrict__ slotc, int* __restrict__ pairpos,
                              float* __restrict__ wrow, short* __restrict__ xb,
                              short* __restrict__ xg) {
  const int t = blockIdx.x, tid = threadIdx.x;
  __shared__ int grs[2];
  if (tid < 2) {
    int e = tidx[t * 2 + tid];
    int slot = atomicAdd(&slotc[e], 1);
    int g = offsets[e] + slot;
    grs[tid] = g;
    pairpos[t * 2 + tid] = g;
    wrow[g] = tw[t * 2 + tid];
  }
  __syncthreads();
  const int g0 = grs[0], g1 = grs[1];
  const float* xr = x + (size_t)t * HDIM;
#pragma unroll
  for (int i = 0; i < HDIM / 256; ++i) {
    int k = tid + i * 256;
    short v = f2bf(xr[k]);
    xb[(size_t)t * HDIM + k] = v;
    xg[(size_t)g0 * HDIM + k] = v;
    xg[(size_t)g1 * HDIM + k] = v;
  }
}

// ---------------- standalone coalesced weight convert (one tile per block)
template <int BN>
__global__ void wconv2_kernel(const float* __restrict__ src, short* __restrict__ dst,
                              const int K, const int N, const int nT, const int kT) {
  __shared__ float lds[32 * (BN + 4)];
  int b = blockIdx.x;
  const int kt = b % kT;
  b /= kT;
  const int nt = b % nT;
  const int slab = b / nT;
  const float* s = src + (size_t)slab * K * N + (size_t)(kt * 32) * N + nt * BN;
  short* d = dst + ((size_t)((slab * nT + nt) * kT + kt)) * BN * 32;
  conv_tile<BN>(s, d, N, threadIdx.x, lds);
}

// ================= merged UP (persistent, 256 thr = 4 waves):
// H = bf16( silu(A*B1) * (A*B3) ).  Block tile 128m x 64n x {G,U}.
// Wave w: m-half (w&1), mat (w>>1); wave tile 64x64.
// Single-barrier depth-3 K-loop; setprio(1) around MFMA cluster (T5).
__launch_bounds__(256, 3)
__global__ void moe_up_k(const short* __restrict__ xg, const short* __restrict__ xb,
                         const short* __restrict__ cw1, const short* __restrict__ cw3,
                         const short* __restrict__ csg, const short* __restrict__ csu,
                         short* __restrict__ hbE, short* __restrict__ hbS,
                         const int* __restrict__ counts, const int* __restrict__ offsets,
                         const int* __restrict__ meta) {
  const int tid = threadIdx.x;
  __shared__ int spre[17];
  __shared__ __align__(16) char pool[49152];
  short (*Ab)[128][32] = (short(*)[128][32])pool;             // [3][128][32]  24KB
  short (*Bb)[128][32] = (short(*)[128][32])(pool + 24576);   // [3][G64|U64][32] 24KB
  float* scratch = (float*)pool;                              // 32KB, epilogue only

  if (tid < 17) spre[tid] = meta[tid];
  __syncthreads();
  const int gemmE = spre[16] * 26;
  const int total = gemmE + 832;

  const int lane = tid & 63;
  const int w = tid >> 6;
  const int wmv = (w & 1) * 64;     // m-half
  const int mat = w >> 1;           // 0=G, 1=U
  const int lrow = lane & 15;
  const int lkg = lane >> 4;
  const int a_ko = (tid & 3) << 3;

  for (int ticket = blockIdx.x; ticket < total; ticket += NPERS) {
    const short* A; const short* b1tile; const short* b3tile; short* H;
    int N, mtile, ntile, rowbase = 0, cnt = 0x7fffffff;
    bool expert;
    if (ticket < gemmE) {
      const int p = ticket / 26;
      const int n = ticket % 26;
      int e = 0;
#pragma unroll
      for (int i = 1; i < 16; ++i) if (p >= spre[i]) e = i;
      const int m = p - spre[e];
      cnt = counts[e];
      rowbase = offsets[e];
      mtile = m * 128;
      A = xg;
      b1tile = cw1 + ((size_t)((e * 26 + n) * 80)) * 2048;
      b3tile = cw3 + ((size_t)((e * 26 + n) * 80)) * 2048;
      H = hbE; N = IDIM; ntile = n * 64; expert = true;
    } else {
      const int s = ticket - gemmE;   // 0..831
      const int n = s % 52;
      const int m = s / 52;           // 0..15
      mtile = m * 128;
      A = xb;
      b1tile = csg + ((size_t)(n * 80)) * 2048;
      b3tile = csu + ((size_t)(n * 80)) * 2048;
      H = hbS; N = ISDIM; ntile = n * 64; expert = false;
    }
    const int K = HDIM;
    const int KT = HDIM / 32;         // 80

    f32x4 acc[4][4];
#pragma unroll
    for (int i = 0; i < 4; ++i)
#pragma unroll
      for (int j = 0; j < 4; ++j) { f32x4 z = {0.f,0.f,0.f,0.f}; acc[i][j] = z; }

    int gr0, gr1;
    {
      int r0 = tid >> 2, r1 = (tid >> 2) + 64;
      gr0 = expert ? (rowbase + mtile + r0) : (mtile + r0);
      gr1 = expert ? (rowbase + mtile + r1) : (mtile + r1);
      if (gr0 > NPAIR - 1) gr0 = NPAIR - 1;
      if (gr1 > NPAIR - 1) gr1 = NPAIR - 1;
    }
    const short* a_src0 = A + (size_t)gr0 * K + a_ko;
    const short* a_src1 = A + (size_t)gr1 * K + a_ko;

#define STAGE_U(kt, buf) do { \
    GLDS16(a_src0 + ((kt) << 5), (short*)Ab[buf] + tid * 8); \
    GLDS16(a_src1 + ((kt) << 5), (short*)Ab[buf] + (tid + 256) * 8); \
    GLDS16(b1tile + (size_t)(kt) * 2048 + tid * 8, (short*)Bb[buf] + tid * 8); \
    GLDS16(b3tile + (size_t)(kt) * 2048 + tid * 8, (short*)Bb[buf] + 2048 + tid * 8); \
  } while (0)

    auto compute = [&](int buf) {
      bf16x8 af[4], bfv[4];
#pragma unroll
      for (int mf = 0; mf < 4; ++mf)
        af[mf] = *reinterpret_cast<const bf16x8*>(&Ab[buf][wmv + mf * 16 + lrow][lkg << 3]);
#pragma unroll
      for (int nf = 0; nf < 4; ++nf) {
        const int nloc = nf * 16 + lrow;
        const int kg = (lkg ^ ((nloc >> 1) & 3)) << 3;
        bfv[nf] = *reinterpret_cast<const bf16x8*>(&Bb[buf][mat * 64 + nloc][kg]);
      }
      __builtin_amdgcn_s_setprio(1);
#pragma unroll
      for (int mf = 0; mf < 4; ++mf)
#pragma unroll
        for (int nf = 0; nf < 4; ++nf)
          acc[mf][nf] = __builtin_amdgcn_mfma_f32_16x16x32_bf16(af[mf], bfv[nf], acc[mf][nf], 0, 0, 0);
      __builtin_amdgcn_s_setprio(0);
    };

    // single-barrier pipelined K-loop (depth-3, stage 2 ahead)
    STAGE_U(0, 0); STAGE_U(1, 1);
    for (int i = 0; i < KT; ++i) {
      if (i + 1 < KT) { VMCNT(4); } else { VMCNT(0); }
      LGKM_BAR();
      if (i + 2 < KT) {
        const int fb = (i + 2) % 3;
        STAGE_U(i + 2, fb);
      }
      compute(i % 3);
    }
    LGKM_BAR();   // all compute reads done before scratch writes

    // epilogue: U-waves export acc to scratch; G-waves fuse silu(g)*u -> H.
    if (mat) {
      float* sc = scratch + (size_t)(w & 1) * 4096;
#pragma unroll
      for (int mf = 0; mf < 4; ++mf)
#pragma unroll
        for (int r = 0; r < 4; ++r) {
          const int row = mf * 16 + ((lane >> 4) << 2) + r;
#pragma unroll
          for (int nf = 0; nf < 4; ++nf)
            sc[row * 64 + nf * 16 + lrow] = acc[mf][nf][r];
        }
    }
    LGKM_BAR();
    if (!mat) {
      const float* sc = scratch + (size_t)(w & 1) * 4096;
#pragma unroll
      for (int mf = 0; mf < 4; ++mf) {
#pragma unroll
        for (int r = 0; r < 4; ++r) {
          const int row = mf * 16 + ((lane >> 4) << 2) + r;
          const int rt = wmv + row;
          if (expert && mtile + rt >= cnt) continue;
          const size_t grow = (size_t)((expert ? rowbase : 0) + mtile + rt);
          const int colb = ntile + lrow;
#pragma unroll
          for (int nf = 0; nf < 4; ++nf) {
            float g = acc[mf][nf][r];
            float u = sc[row * 64 + nf * 16 + lrow];
            H[grow * N + colb + nf * 16] = f2bf(g / (1.f + expf(-g)) * u);
          }
        }
      }
    }
    LGKM_BAR();   // scratch reads complete before next ticket's staging
#undef STAGE_U
  }
}

// ================= merged DOWN (persistent, 256 thr = 4 waves): Out = A*B.
// Block tile 128m x 128n; wave tile 64x64.  Single-barrier K-loop + setprio.
// Shared tiles (KT=104) ticketed FIRST so long tiles never start in the tail.
__launch_bounds__(256, 3)
__global__ void moe_dn_k(const short* __restrict__ hbE, const short* __restrict__ hbS,
                         const short* __restrict__ cw2, const short* __restrict__ csd,
                         float* __restrict__ pairs, float* __restrict__ outb,
                         const int* __restrict__ counts, const int* __restrict__ offsets,
                         const float* __restrict__ wrow, const int* __restrict__ meta) {
  const int tid = threadIdx.x;
  __shared__ int spre[17];
  __shared__ short Ab[3][128][32];   // 24 KB, linear
  __shared__ short Bb[3][128][32];   // 24 KB, swizzled [n][k] tile-linear

  if (tid < 17) spre[tid] = meta[tid];
  __syncthreads();
  const int total = spre[16] * 20 + 320;

  const int lane = tid & 63;
  const int w = tid >> 6;
  const int wm = (w >> 1) * 64;
  const int wn = (w & 1) * 64;
  const int lrow = lane & 15;
  const int lkg = lane >> 4;
  const int a_ko = (tid & 3) << 3;

  for (int ticket = blockIdx.x; ticket < total; ticket += NPERS) {
    const short* A; const short* btile; float* Out;
    int K, KT, mtile, ntile, rowbase = 0, cnt = 0x7fffffff;
    bool expert;
    if (ticket < 320) {               // shared first (long tiles)
      const int n = ticket % 20;
      const int m = ticket / 20;      // 0..15
      mtile = m * 128;
      A = hbS;
      btile = csd + ((size_t)(n * 104)) * 4096;
      Out = outb; K = ISDIM; KT = ISDIM / 32; ntile = n * 128; expert = false; // KT=104
    } else {
      const int te = ticket - 320;
      const int p = te / 20;
      const int n = te % 20;
      int e = 0;
#pragma unroll
      for (int i = 1; i < 16; ++i) if (p >= spre[i]) e = i;
      const int m = p - spre[e];
      cnt = counts[e];
      rowbase = offsets[e];
      mtile = m * 128;
      A = hbE;
      btile = cw2 + ((size_t)((e * 20 + n) * 52)) * 4096;
      Out = pairs; K = IDIM; KT = IDIM / 32; ntile = n * 128; expert = true;   // KT=52
    }

    f32x4 acc[4][4];
#pragma unroll
    for (int i = 0; i < 4; ++i)
#pragma unroll
      for (int j = 0; j < 4; ++j) { f32x4 z = {0.f,0.f,0.f,0.f}; acc[i][j] = z; }

    int gr0, gr1;
    {
      int r0 = tid >> 2, r1 = (tid >> 2) + 64;
      gr0 = expert ? (rowbase + mtile + r0) : (mtile + r0);
      gr1 = expert ? (rowbase + mtile + r1) : (mtile + r1);
      if (gr0 > NPAIR - 1) gr0 = NPAIR - 1;
      if (gr1 > NPAIR - 1) gr1 = NPAIR - 1;
    }
    const short* a_src0 = A + (size_t)gr0 * K + a_ko;
    const short* a_src1 = A + (size_t)gr1 * K + a_ko;

#define STAGE_D(kt, buf) do { \
    GLDS16(a_src0 + ((kt) << 5), (short*)Ab[buf] + tid * 8); \
    GLDS16(a_src1 + ((kt) << 5), (short*)Ab[buf] + (tid + 256) * 8); \
    GLDS16(btile + (size_t)(kt) * 4096 + tid * 8, (short*)Bb[buf] + tid * 8); \
    GLDS16(btile + (size_t)(kt) * 4096 + (tid + 256) * 8, (short*)Bb[buf] + (tid + 256) * 8); \
  } while (0)

    auto compute = [&](int buf) {
      bf16x8 af[4], bfv[4];
#pragma unroll
      for (int mf = 0; mf < 4; ++mf)
        af[mf] = *reinterpret_cast<const bf16x8*>(&Ab[buf][wm + mf * 16 + lrow][lkg << 3]);
#pragma unroll
      for (int nf = 0; nf < 4; ++nf) {
        const int n = wn + nf * 16 + lrow;
        const int kg = (lkg ^ ((n >> 1) & 3)) << 3;
        bfv[nf] = *reinterpret_cast<const bf16x8*>(&Bb[buf][n][kg]);
      }
      __builtin_amdgcn_s_setprio(1);
#pragma unroll
      for (int mf = 0; mf < 4; ++mf)
#pragma unroll
        for (int nf = 0; nf < 4; ++nf)
          acc[mf][nf] = __builtin_amdgcn_mfma_f32_16x16x32_bf16(af[mf], bfv[nf], acc[mf][nf], 0, 0, 0);
      __builtin_amdgcn_s_setprio(0);
    };

    // single-barrier pipelined K-loop (depth-3, stage 2 ahead)
    STAGE_D(0, 0); STAGE_D(1, 1);
    for (int i = 0; i < KT; ++i) {
      if (i + 1 < KT) { VMCNT(4); } else { VMCNT(0); }
      LGKM_BAR();
      if (i + 2 < KT) {
        const int fb = (i + 2) % 3;
        STAGE_D(i + 2, fb);
      }
      compute(i % 3);
    }

#pragma unroll
    for (int mf = 0; mf < 4; ++mf) {
#pragma unroll
      for (int r = 0; r < 4; ++r) {
        const int rt = wm + mf * 16 + ((lane >> 4) << 2) + r;
        const int colb = ntile + wn + lrow;
        if (expert) {
          if (mtile + rt < cnt) {
            const int gr = rowbase + mtile + rt;
            const float sc = wrow[gr];
            float* o = Out + (size_t)gr * HDIM + colb;
#pragma unroll
            for (int nf = 0; nf < 4; ++nf) o[nf * 16] = sc * acc[mf][nf][r];
          }
        } else {
          float* o = Out + (size_t)(mtile + rt) * HDIM + colb;
#pragma unroll
          for (int nf = 0; nf < 4; ++nf) o[nf * 16] = acc[mf][nf][r];
        }
      }
    }
    LGKM_BAR();   // final compute reads complete before next ticket's staging
#undef STAGE_D
  }
}

// ---------------- final combine: out[t] += pairs[g0] + pairs[g1]
__global__ void combine_kernel(float* __restrict__ out, const float* __restrict__ pairs,
                               const int* __restrict__ pairpos) {
  const int t = blockIdx.x;
  const int g0 = pairpos[t * 2], g1 = pairpos[t * 2 + 1];
  const f32x4* p0 = (const f32x4*)(pairs + (size_t)g0 * HDIM);
  const f32x4* p1 = (const f32x4*)(pairs + (size_t)g1 * HDIM);
  f32x4* o = (f32x4*)(out + (size_t)t * HDIM);
  for (int c = threadIdx.x; c < HDIM / 4; c += 256)
    o[c] = o[c] + p0[c] + p1[c];
}

extern "C" void kernel_launch(void* const* d_in, const int* in_sizes, int n_in,
                              void* d_out, int out_size, void* d_ws, size_t ws_size,
                              hipStream_t stream) {
  const float* x  = (const float*)d_in[0];
  const float* rw = (const float*)d_in[1];
  const float* w1 = (const float*)d_in[2];
  const float* w3 = (const float*)d_in[3];
  const float* w2 = (const float*)d_in[4];
  const float* sg = (const float*)d_in[5];
  const float* su = (const float*)d_in[6];
  const float* sd = (const float*)d_in[7];
  float* out = (float*)d_out;
  (void)in_sizes; (void)n_in; (void)out_size; (void)ws_size;

  char* ws = (char*)d_ws;
  size_t off = 0;
  auto alloc = [&](size_t bytes) -> void* {
    void* p = ws + off;
    off = (off + bytes + 255) & ~(size_t)255;
    return p;
  };
  int*   counts  = (int*)alloc(NEXP * 4);          // @0
  int*   slotc   = (int*)alloc(NEXP * 4);          // @256
  int*   offsets = (int*)alloc(NEXP * 4);
  int*   meta    = (int*)alloc(32 * 4);
  int*   tidx    = (int*)alloc(NPAIR * 4);
  float* tw      = (float*)alloc(NPAIR * 4);
  float* wrowv   = (float*)alloc(NPAIR * 4);
  int*   pairpos = (int*)alloc(NPAIR * 4);
  short* xb      = (short*)alloc((size_t)TOKENS * HDIM * 2);
  short* xg      = (short*)alloc((size_t)NPAIR * HDIM * 2);
  short* hbE     = (short*)alloc((size_t)NPAIR * IDIM * 2);
  short* hbS     = (short*)alloc((size_t)TOKENS * ISDIM * 2);
  float* pairs   = (float*)alloc((size_t)NPAIR * HDIM * 4);
  // converted-weight regions (phase-reused): cwA holds w1' then w2'; cwS1 sg' then sd'
  short* cwA  = (short*)alloc((size_t)NEXP * HDIM * IDIM * 2);   // 136.3 MB
  short* cwB  = (short*)alloc((size_t)NEXP * HDIM * IDIM * 2);   // 136.3 MB
  short* cwS1 = (short*)alloc((size_t)HDIM * ISDIM * 2);         // 17.0 MB
  short* cwS2 = (short*)alloc((size_t)HDIM * ISDIM * 2);         // 17.0 MB

  hipMemsetAsync(d_ws, 0, 512, stream);  // zero counts + slotc

  router_kernel<<<dim3(TOKENS), dim3(64), 0, stream>>>(x, rw, counts, tidx, tw);
  scan_kernel<<<dim3(1), dim3(64), 0, stream>>>(counts, offsets, meta);
  gather_kernel<<<dim3(TOKENS), dim3(256), 0, stream>>>(x, tidx, tw, offsets, slotc,
                                                        pairpos, wrowv, xb, xg);

  // convert up-phase weights (coalesced LDS-transpose)
  wconv2_kernel<64><<<dim3(NEXP * 26 * 80), dim3(256), 0, stream>>>(w1, cwA, HDIM, IDIM, 26, 80);
  wconv2_kernel<64><<<dim3(NEXP * 26 * 80), dim3(256), 0, stream>>>(w3, cwB, HDIM, IDIM, 26, 80);
  wconv2_kernel<64><<<dim3(52 * 80), dim3(256), 0, stream>>>(sg, cwS1, HDIM, ISDIM, 52, 80);
  wconv2_kernel<64><<<dim3(52 * 80), dim3(256), 0, stream>>>(su, cwS2, HDIM, ISDIM, 52, 80);

  // merged up: persistent 768 blocks over compact ticket space
  moe_up_k<<<dim3(NPERS), dim3(256), 0, stream>>>(
      xg, xb, cwA, cwB, cwS1, cwS2, hbE, hbS, counts, offsets, meta);

  // convert down-phase weights into the freed regions
  wconv2_kernel<128><<<dim3(NEXP * 20 * 52), dim3(256), 0, stream>>>(w2, cwA, IDIM, HDIM, 20, 52);
  wconv2_kernel<128><<<dim3(20 * 104), dim3(256), 0, stream>>>(sd, cwS1, ISDIM, HDIM, 20, 104);

  // merged down: persistent 768 blocks
  moe_dn_k<<<dim3(NPERS), dim3(256), 0, stream>>>(
      hbE, hbS, cwA, cwS1, pairs, out, counts, offsets, wrowv, meta);

  combine_kernel<<<dim3(TOKENS), dim3(256), 0, stream>>>(out, pairs, pairpos);
}

// Round 16
// 781.277 us; speedup vs baseline: 1.0940x; 1.0017x over previous
//
#include <hip/hip_runtime.h>
#include <hip/hip_bf16.h>

#define TOKENS 2048
#define HDIM   2560
#define NEXP   16
#define IDIM   1664
#define ISDIM  3328
#define NPAIR  (TOKENS*2)
#define NPERS  768    // persistent blocks (3/CU x 256)

typedef float  f32x4   __attribute__((ext_vector_type(4)));
typedef __bf16 bf16x8  __attribute__((ext_vector_type(8)));
typedef short  short8v __attribute__((ext_vector_type(8)));

#define GLDS16(g, l) __builtin_amdgcn_global_load_lds( \
    (const __attribute__((address_space(1))) unsigned int*)(g), \
    (__attribute__((address_space(3))) unsigned int*)(l), 16, 0, 0)

#define VMCNT(n) asm volatile("s_waitcnt vmcnt(" #n ")" ::: "memory")
#define LGKM_BAR() do { \
    asm volatile("s_waitcnt lgkmcnt(0)" ::: "memory"); \
    __builtin_amdgcn_sched_barrier(0); \
    __builtin_amdgcn_s_barrier(); \
    __builtin_amdgcn_sched_barrier(0); \
  } while (0)

__device__ __forceinline__ short f2bf(float f) {
  unsigned u = __builtin_bit_cast(unsigned, f);
  u += 0x7FFFu + ((u >> 16) & 1u);          // RNE to bf16
  return (short)(u >> 16);
}

// ---- coalesced conv-tile: 32k x BN fp32 (N-contig rows) -> bf16 tile-linear,
// pre-swizzled (unit u = n*4 + (koct ^ ((n>>1)&3)), byte j = k&7).
template <int BN>
__device__ __forceinline__ void conv_tile(const float* __restrict__ src,
                                          short* __restrict__ dst,
                                          const int N, const int tid,
                                          float* __restrict__ lds) {
  const int FPT = BN / 8;                    // floats per thread (8 or 16)
#pragma unroll
  for (int c4 = 0; c4 < FPT / 4; ++c4) {
    const int f = tid * FPT + c4 * 4;
    const int row = f / BN, col = f % BN;
    f32x4 v = *reinterpret_cast<const f32x4*>(src + (size_t)row * N + col);
    *reinterpret_cast<f32x4*>(lds + row * (BN + 4) + col) = v;
  }
  __syncthreads();
#pragma unroll
  for (int q = 0; q < BN / 64; ++q) {
    const int uidx = tid + q * 256;
    const int n = uidx >> 2, u = uidx & 3;
    const int koct = u ^ ((n >> 1) & 3);
    short8v o;
#pragma unroll
    for (int j = 0; j < 8; ++j) o[j] = f2bf(lds[(koct * 8 + j) * (BN + 4) + n]);
    *reinterpret_cast<short8v*>(dst + uidx * 8) = o;
  }
  __syncthreads();
}

// ---------------- router: fp32 logits, softmax-top2-renorm == sigmoid(l0-l1)
__global__ void router_kernel(const float* __restrict__ x, const float* __restrict__ rw,
                              int* __restrict__ counts, int* __restrict__ tidx,
                              float* __restrict__ tw) {
  const int t = blockIdx.x;
  const int lane = threadIdx.x;
  float acc[NEXP];
#pragma unroll
  for (int e = 0; e < NEXP; ++e) acc[e] = 0.f;
  const float* xr = x + (size_t)t * HDIM;
  for (int k = lane; k < HDIM; k += 64) {
    float xv = xr[k];
#pragma unroll
    for (int e = 0; e < NEXP; ++e) acc[e] += xv * rw[e * HDIM + k];
  }
#pragma unroll
  for (int e = 0; e < NEXP; ++e) {
#pragma unroll
    for (int o = 32; o > 0; o >>= 1) acc[e] += __shfl_down(acc[e], o);
  }
  if (lane == 0) {
    int i0 = 0; float v0 = acc[0];
#pragma unroll
    for (int e = 1; e < NEXP; ++e) if (acc[e] > v0) { v0 = acc[e]; i0 = e; }
    int i1 = -1; float v1 = -3.4e38f;
#pragma unroll
    for (int e = 0; e < NEXP; ++e) if (e != i0 && acc[e] > v1) { v1 = acc[e]; i1 = e; }
    float w0 = 1.f / (1.f + expf(v1 - v0));
    tidx[t * 2] = i0; tidx[t * 2 + 1] = i1;
    tw[t * 2] = w0;   tw[t * 2 + 1] = 1.f - w0;
    atomicAdd(&counts[i0], 1);
    atomicAdd(&counts[i1], 1);
  }
}

// scan + tile-queue metadata: meta[0..15]=panel prefix, meta[16]=total panels
__global__ void scan_kernel(const int* __restrict__ counts, int* __restrict__ offsets,
                            int* __restrict__ meta) {
  if (threadIdx.x == 0) {
    int a = 0, p = 0;
    for (int e = 0; e < NEXP; ++e) {
      offsets[e] = a;
      meta[e] = p;
      a += counts[e];
      p += (counts[e] + 127) >> 7;     // ceil(cnt/128) panels
    }
    meta[16] = p;
  }
}

// ---------------- bucket pairs + gather bf16 activations
__global__ void gather_kernel(const float* __restrict__ x, const int* __restrict__ tidx,
                              const float* __restrict__ tw, const int* __restrict__ offsets,
                              int* __restrict__ slotc, int* __restrict__ pairpos,
                              float* __restrict__ wrow, short* __restrict__ xb,
                              short* __restrict__ xg) {
  const int t = blockIdx.x, tid = threadIdx.x;
  __shared__ int grs[2];
  if (tid < 2) {
    int e = tidx[t * 2 + tid];
    int slot = atomicAdd(&slotc[e], 1);
    int g = offsets[e] + slot;
    grs[tid] = g;
    pairpos[t * 2 + tid] = g;
    wrow[g] = tw[t * 2 + tid];
  }
  __syncthreads();
  const int g0 = grs[0], g1 = grs[1];
  const float* xr = x + (size_t)t * HDIM;
#pragma unroll
  for (int i = 0; i < HDIM / 256; ++i) {
    int k = tid + i * 256;
    short v = f2bf(xr[k]);
    xb[(size_t)t * HDIM + k] = v;
    xg[(size_t)g0 * HDIM + k] = v;
    xg[(size_t)g1 * HDIM + k] = v;
  }
}

// ---------------- standalone coalesced weight convert (one tile per block)
template <int BN>
__global__ void wconv2_kernel(const float* __restrict__ src, short* __restrict__ dst,
                              const int K, const int N, const int nT, const int kT) {
  __shared__ float lds[32 * (BN + 4)];
  int b = blockIdx.x;
  const int kt = b % kT;
  b /= kT;
  const int nt = b % nT;
  const int slab = b / nT;
  const float* s = src + (size_t)slab * K * N + (size_t)(kt * 32) * N + nt * BN;
  short* d = dst + ((size_t)((slab * nT + nt) * kT + kt)) * BN * 32;
  conv_tile<BN>(s, d, N, threadIdx.x, lds);
}

// ================= merged UP (persistent, 256 thr = 4 waves):
// H = bf16( silu(A*B1) * (A*B3) ).  Block tile 128m x 64n x {G,U}.
// Wave w: m-half (w&1), mat (w>>1); wave tile 64x64.
// ASYMMETRIC-DEPTH pipeline: A (L3-hot) depth-2, B (HBM-cold) depth-4 in the
// same 48KB.  Per step: issue A(i+1), B(i+3); barrier wait VMCNT(2) leaves
// B(i+2..i+3) in flight -> B gets ~3 steps of latency budget.
__launch_bounds__(256, 3)
__global__ void moe_up_k(const short* __restrict__ xg, const short* __restrict__ xb,
                         const short* __restrict__ cw1, const short* __restrict__ cw3,
                         const short* __restrict__ csg, const short* __restrict__ csu,
                         short* __restrict__ hbE, short* __restrict__ hbS,
                         const int* __restrict__ counts, const int* __restrict__ offsets,
                         const int* __restrict__ meta) {
  const int tid = threadIdx.x;
  __shared__ int spre[17];
  __shared__ __align__(16) char pool[49152];
  short (*Ab)[128][32] = (short(*)[128][32])pool;             // [2][128][32]  16KB
  short (*Bb)[128][32] = (short(*)[128][32])(pool + 16384);   // [4][G64|U64][32] 32KB
  float* scratch = (float*)pool;                              // 32KB, epilogue only

  if (tid < 17) spre[tid] = meta[tid];
  __syncthreads();
  const int gemmE = spre[16] * 26;
  const int total = gemmE + 832;

  const int lane = tid & 63;
  const int w = tid >> 6;
  const int wmv = (w & 1) * 64;     // m-half
  const int mat = w >> 1;           // 0=G, 1=U
  const int lrow = lane & 15;
  const int lkg = lane >> 4;
  const int a_ko = (tid & 3) << 3;

  for (int ticket = blockIdx.x; ticket < total; ticket += NPERS) {
    const short* A; const short* b1tile; const short* b3tile; short* H;
    int N, mtile, ntile, rowbase = 0, cnt = 0x7fffffff;
    bool expert;
    if (ticket < gemmE) {
      const int p = ticket / 26;
      const int n = ticket % 26;
      int e = 0;
#pragma unroll
      for (int i = 1; i < 16; ++i) if (p >= spre[i]) e = i;
      const int m = p - spre[e];
      cnt = counts[e];
      rowbase = offsets[e];
      mtile = m * 128;
      A = xg;
      b1tile = cw1 + ((size_t)((e * 26 + n) * 80)) * 2048;
      b3tile = cw3 + ((size_t)((e * 26 + n) * 80)) * 2048;
      H = hbE; N = IDIM; ntile = n * 64; expert = true;
    } else {
      const int s = ticket - gemmE;   // 0..831
      const int n = s % 52;
      const int m = s / 52;           // 0..15
      mtile = m * 128;
      A = xb;
      b1tile = csg + ((size_t)(n * 80)) * 2048;
      b3tile = csu + ((size_t)(n * 80)) * 2048;
      H = hbS; N = ISDIM; ntile = n * 64; expert = false;
    }
    const int K = HDIM;
    const int KT = HDIM / 32;         // 80

    f32x4 acc[4][4];
#pragma unroll
    for (int i = 0; i < 4; ++i)
#pragma unroll
      for (int j = 0; j < 4; ++j) { f32x4 z = {0.f,0.f,0.f,0.f}; acc[i][j] = z; }

    int gr0, gr1;
    {
      int r0 = tid >> 2, r1 = (tid >> 2) + 64;
      gr0 = expert ? (rowbase + mtile + r0) : (mtile + r0);
      gr1 = expert ? (rowbase + mtile + r1) : (mtile + r1);
      if (gr0 > NPAIR - 1) gr0 = NPAIR - 1;
      if (gr1 > NPAIR - 1) gr1 = NPAIR - 1;
    }
    const short* a_src0 = A + (size_t)gr0 * K + a_ko;
    const short* a_src1 = A + (size_t)gr1 * K + a_ko;

#define STAGEA_U(kt) do { \
    GLDS16(a_src0 + ((kt) << 5), (short*)Ab[(kt) & 1] + tid * 8); \
    GLDS16(a_src1 + ((kt) << 5), (short*)Ab[(kt) & 1] + (tid + 256) * 8); \
  } while (0)
#define STAGEB_U(kt) do { \
    GLDS16(b1tile + (size_t)(kt) * 2048 + tid * 8, (short*)Bb[(kt) & 3] + tid * 8); \
    GLDS16(b3tile + (size_t)(kt) * 2048 + tid * 8, (short*)Bb[(kt) & 3] + 2048 + tid * 8); \
  } while (0)

    auto compute = [&](int ab, int bb) {
      bf16x8 af[4], bfv[4];
#pragma unroll
      for (int mf = 0; mf < 4; ++mf)
        af[mf] = *reinterpret_cast<const bf16x8*>(&Ab[ab][wmv + mf * 16 + lrow][lkg << 3]);
#pragma unroll
      for (int nf = 0; nf < 4; ++nf) {
        const int nloc = nf * 16 + lrow;
        const int kg = (lkg ^ ((nloc >> 1) & 3)) << 3;
        bfv[nf] = *reinterpret_cast<const bf16x8*>(&Bb[bb][mat * 64 + nloc][kg]);
      }
      __builtin_amdgcn_s_setprio(1);
#pragma unroll
      for (int mf = 0; mf < 4; ++mf)
#pragma unroll
        for (int nf = 0; nf < 4; ++nf)
          acc[mf][nf] = __builtin_amdgcn_mfma_f32_16x16x32_bf16(af[mf], bfv[nf], acc[mf][nf], 0, 0, 0);
      __builtin_amdgcn_s_setprio(0);
    };

    // prologue: A(0) first, then B(0..2) -> wait newest-needed B(0): VMCNT(4)
    STAGEA_U(0);
    STAGEB_U(0); STAGEB_U(1); STAGEB_U(2);
    VMCNT(4);
    LGKM_BAR();
    for (int i = 0; i < KT; ++i) {
      if (i) {
        if (i + 2 < KT) { VMCNT(2); } else { VMCNT(0); }
        LGKM_BAR();
      }
      if (i + 1 < KT) STAGEA_U(i + 1);
      if (i + 3 < KT) STAGEB_U(i + 3);
      compute(i & 1, i & 3);
    }
    LGKM_BAR();   // all compute reads done before scratch writes

    // epilogue: U-waves export acc to scratch; G-waves fuse silu(g)*u -> H.
    if (mat) {
      float* sc = scratch + (size_t)(w & 1) * 4096;
#pragma unroll
      for (int mf = 0; mf < 4; ++mf)
#pragma unroll
        for (int r = 0; r < 4; ++r) {
          const int row = mf * 16 + ((lane >> 4) << 2) + r;
#pragma unroll
          for (int nf = 0; nf < 4; ++nf)
            sc[row * 64 + nf * 16 + lrow] = acc[mf][nf][r];
        }
    }
    LGKM_BAR();
    if (!mat) {
      const float* sc = scratch + (size_t)(w & 1) * 4096;
#pragma unroll
      for (int mf = 0; mf < 4; ++mf) {
#pragma unroll
        for (int r = 0; r < 4; ++r) {
          const int row = mf * 16 + ((lane >> 4) << 2) + r;
          const int rt = wmv + row;
          if (expert && mtile + rt >= cnt) continue;
          const size_t grow = (size_t)((expert ? rowbase : 0) + mtile + rt);
          const int colb = ntile + lrow;
#pragma unroll
          for (int nf = 0; nf < 4; ++nf) {
            float g = acc[mf][nf][r];
            float u = sc[row * 64 + nf * 16 + lrow];
            H[grow * N + colb + nf * 16] = f2bf(g / (1.f + expf(-g)) * u);
          }
        }
      }
    }
    LGKM_BAR();   // scratch reads complete before next ticket's staging
#undef STAGEA_U
#undef STAGEB_U
  }
}

// ================= merged DOWN (persistent, 256 thr = 4 waves): Out = A*B.
// Block tile 128m x 128n; wave tile 64x64.  Same asymmetric-depth pipeline.
// Shared tiles (KT=104) ticketed FIRST so long tiles never start in the tail.
__launch_bounds__(256, 3)
__global__ void moe_dn_k(const short* __restrict__ hbE, const short* __restrict__ hbS,
                         const short* __restrict__ cw2, const short* __restrict__ csd,
                         float* __restrict__ pairs, float* __restrict__ outb,
                         const int* __restrict__ counts, const int* __restrict__ offsets,
                         const float* __restrict__ wrow, const int* __restrict__ meta) {
  const int tid = threadIdx.x;
  __shared__ int spre[17];
  __shared__ short Ab[2][128][32];   // 16 KB, linear
  __shared__ short Bb[4][128][32];   // 32 KB, swizzled [n][k] tile-linear

  if (tid < 17) spre[tid] = meta[tid];
  __syncthreads();
  const int total = spre[16] * 20 + 320;

  const int lane = tid & 63;
  const int w = tid >> 6;
  const int wm = (w >> 1) * 64;
  const int wn = (w & 1) * 64;
  const int lrow = lane & 15;
  const int lkg = lane >> 4;
  const int a_ko = (tid & 3) << 3;

  for (int ticket = blockIdx.x; ticket < total; ticket += NPERS) {
    const short* A; const short* btile; float* Out;
    int K, KT, mtile, ntile, rowbase = 0, cnt = 0x7fffffff;
    bool expert;
    if (ticket < 320) {               // shared first (long tiles)
      const int n = ticket % 20;
      const int m = ticket / 20;      // 0..15
      mtile = m * 128;
      A = hbS;
      btile = csd + ((size_t)(n * 104)) * 4096;
      Out = outb; K = ISDIM; KT = ISDIM / 32; ntile = n * 128; expert = false; // KT=104
    } else {
      const int te = ticket - 320;
      const int p = te / 20;
      const int n = te % 20;
      int e = 0;
#pragma unroll
      for (int i = 1; i < 16; ++i) if (p >= spre[i]) e = i;
      const int m = p - spre[e];
      cnt = counts[e];
      rowbase = offsets[e];
      mtile = m * 128;
      A = hbE;
      btile = cw2 + ((size_t)((e * 20 + n) * 52)) * 4096;
      Out = pairs; K = IDIM; KT = IDIM / 32; ntile = n * 128; expert = true;   // KT=52
    }

    f32x4 acc[4][4];
#pragma unroll
    for (int i = 0; i < 4; ++i)
#pragma unroll
      for (int j = 0; j < 4; ++j) { f32x4 z = {0.f,0.f,0.f,0.f}; acc[i][j] = z; }

    int gr0, gr1;
    {
      int r0 = tid >> 2, r1 = (tid >> 2) + 64;
      gr0 = expert ? (rowbase + mtile + r0) : (mtile + r0);
      gr1 = expert ? (rowbase + mtile + r1) : (mtile + r1);
      if (gr0 > NPAIR - 1) gr0 = NPAIR - 1;
      if (gr1 > NPAIR - 1) gr1 = NPAIR - 1;
    }
    const short* a_src0 = A + (size_t)gr0 * K + a_ko;
    const short* a_src1 = A + (size_t)gr1 * K + a_ko;

#define STAGEA_D(kt) do { \
    GLDS16(a_src0 + ((kt) << 5), (short*)Ab[(kt) & 1] + tid * 8); \
    GLDS16(a_src1 + ((kt) << 5), (short*)Ab[(kt) & 1] + (tid + 256) * 8); \
  } while (0)
#define STAGEB_D(kt) do { \
    GLDS16(btile + (size_t)(kt) * 4096 + tid * 8, (short*)Bb[(kt) & 3] + tid * 8); \
    GLDS16(btile + (size_t)(kt) * 4096 + (tid + 256) * 8, (short*)Bb[(kt) & 3] + (tid + 256) * 8); \
  } while (0)

    auto compute = [&](int ab, int bb) {
      bf16x8 af[4], bfv[4];
#pragma unroll
      for (int mf = 0; mf < 4; ++mf)
        af[mf] = *reinterpret_cast<const bf16x8*>(&Ab[ab][wm + mf * 16 + lrow][lkg << 3]);
#pragma unroll
      for (int nf = 0; nf < 4; ++nf) {
        const int n = wn + nf * 16 + lrow;
        const int kg = (lkg ^ ((n >> 1) & 3)) << 3;
        bfv[nf] = *reinterpret_cast<const bf16x8*>(&Bb[bb][n][kg]);
      }
      __builtin_amdgcn_s_setprio(1);
#pragma unroll
      for (int mf = 0; mf < 4; ++mf)
#pragma unroll
        for (int nf = 0; nf < 4; ++nf)
          acc[mf][nf] = __builtin_amdgcn_mfma_f32_16x16x32_bf16(af[mf], bfv[nf], acc[mf][nf], 0, 0, 0);
      __builtin_amdgcn_s_setprio(0);
    };

    STAGEA_D(0);
    STAGEB_D(0); STAGEB_D(1); STAGEB_D(2);
    VMCNT(4);
    LGKM_BAR();
    for (int i = 0; i < KT; ++i) {
      if (i) {
        if (i + 2 < KT) { VMCNT(2); } else { VMCNT(0); }
        LGKM_BAR();
      }
      if (i + 1 < KT) STAGEA_D(i + 1);
      if (i + 3 < KT) STAGEB_D(i + 3);
      compute(i & 1, i & 3);
    }

#pragma unroll
    for (int mf = 0; mf < 4; ++mf) {
#pragma unroll
      for (int r = 0; r < 4; ++r) {
        const int rt = wm + mf * 16 + ((lane >> 4) << 2) + r;
        const int colb = ntile + wn + lrow;
        if (expert) {
          if (mtile + rt < cnt) {
            const int gr = rowbase + mtile + rt;
            const float sc = wrow[gr];
            float* o = Out + (size_t)gr * HDIM + colb;
#pragma unroll
            for (int nf = 0; nf < 4; ++nf) o[nf * 16] = sc * acc[mf][nf][r];
          }
        } else {
          float* o = Out + (size_t)(mtile + rt) * HDIM + colb;
#pragma unroll
          for (int nf = 0; nf < 4; ++nf) o[nf * 16] = acc[mf][nf][r];
        }
      }
    }
    LGKM_BAR();   // final compute reads complete before next ticket's staging
#undef STAGEA_D
#undef STAGEB_D
  }
}

// ---------------- final combine: out[t] += pairs[g0] + pairs[g1]
__global__ void combine_kernel(float* __restrict__ out, const float* __restrict__ pairs,
                               const int* __restrict__ pairpos) {
  const int t = blockIdx.x;
  const int g0 = pairpos[t * 2], g1 = pairpos[t * 2 + 1];
  const f32x4* p0 = (const f32x4*)(pairs + (size_t)g0 * HDIM);
  const f32x4* p1 = (const f32x4*)(pairs + (size_t)g1 * HDIM);
  f32x4* o = (f32x4*)(out + (size_t)t * HDIM);
  for (int c = threadIdx.x; c < HDIM / 4; c += 256)
    o[c] = o[c] + p0[c] + p1[c];
}

extern "C" void kernel_launch(void* const* d_in, const int* in_sizes, int n_in,
                              void* d_out, int out_size, void* d_ws, size_t ws_size,
                              hipStream_t stream) {
  const float* x  = (const float*)d_in[0];
  const float* rw = (const float*)d_in[1];
  const float* w1 = (const float*)d_in[2];
  const float* w3 = (const float*)d_in[3];
  const float* w2 = (const float*)d_in[4];
  const float* sg = (const float*)d_in[5];
  const float* su = (const float*)d_in[6];
  const float* sd = (const float*)d_in[7];
  float* out = (float*)d_out;
  (void)in_sizes; (void)n_in; (void)out_size; (void)ws_size;

  char* ws = (char*)d_ws;
  size_t off = 0;
  auto alloc = [&](size_t bytes) -> void* {
    void* p = ws + off;
    off = (off + bytes + 255) & ~(size_t)255;
    return p;
  };
  int*   counts  = (int*)alloc(NEXP * 4);          // @0
  int*   slotc   = (int*)alloc(NEXP * 4);          // @256
  int*   offsets = (int*)alloc(NEXP * 4);
  int*   meta    = (int*)alloc(32 * 4);
  int*   tidx    = (int*)alloc(NPAIR * 4);
  float* tw      = (float*)alloc(NPAIR * 4);
  float* wrowv   = (float*)alloc(NPAIR * 4);
  int*   pairpos = (int*)alloc(NPAIR * 4);
  short* xb      = (short*)alloc((size_t)TOKENS * HDIM * 2);
  short* xg      = (short*)alloc((size_t)NPAIR * HDIM * 2);
  short* hbE     = (short*)alloc((size_t)NPAIR * IDIM * 2);
  short* hbS     = (short*)alloc((size_t)TOKENS * ISDIM * 2);
  float* pairs   = (float*)alloc((size_t)NPAIR * HDIM * 4);
  // converted-weight regions (phase-reused): cwA holds w1' then w2'; cwS1 sg' then sd'
  short* cwA  = (short*)alloc((size_t)NEXP * HDIM * IDIM * 2);   // 136.3 MB
  short* cwB  = (short*)alloc((size_t)NEXP * HDIM * IDIM * 2);   // 136.3 MB
  short* cwS1 = (short*)alloc((size_t)HDIM * ISDIM * 2);         // 17.0 MB
  short* cwS2 = (short*)alloc((size_t)HDIM * ISDIM * 2);         // 17.0 MB

  hipMemsetAsync(d_ws, 0, 512, stream);  // zero counts + slotc

  router_kernel<<<dim3(TOKENS), dim3(64), 0, stream>>>(x, rw, counts, tidx, tw);
  scan_kernel<<<dim3(1), dim3(64), 0, stream>>>(counts, offsets, meta);
  gather_kernel<<<dim3(TOKENS), dim3(256), 0, stream>>>(x, tidx, tw, offsets, slotc,
                                                        pairpos, wrowv, xb, xg);

  // convert up-phase weights (coalesced LDS-transpose)
  wconv2_kernel<64><<<dim3(NEXP * 26 * 80), dim3(256), 0, stream>>>(w1, cwA, HDIM, IDIM, 26, 80);
  wconv2_kernel<64><<<dim3(NEXP * 26 * 80), dim3(256), 0, stream>>>(w3, cwB, HDIM, IDIM, 26, 80);
  wconv2_kernel<64><<<dim3(52 * 80), dim3(256), 0, stream>>>(sg, cwS1, HDIM, ISDIM, 52, 80);
  wconv2_kernel<64><<<dim3(52 * 80), dim3(256), 0, stream>>>(su, cwS2, HDIM, ISDIM, 52, 80);

  // merged up: persistent 768 blocks over compact ticket space
  moe_up_k<<<dim3(NPERS), dim3(256), 0, stream>>>(
      xg, xb, cwA, cwB, cwS1, cwS2, hbE, hbS, counts, offsets, meta);

  // convert down-phase weights into the freed regions
  wconv2_kernel<128><<<dim3(NEXP * 20 * 52), dim3(256), 0, stream>>>(w2, cwA, IDIM, HDIM, 20, 52);
  wconv2_kernel<128><<<dim3(20 * 104), dim3(256), 0, stream>>>(sd, cwS1, ISDIM, HDIM, 20, 104);

  // merged down: persistent 768 blocks
  moe_dn_k<<<dim3(NPERS), dim3(256), 0, stream>>>(
      hbE, hbS, cwA, cwS1, pairs, out, counts, offsets, wrowv, meta);

  combine_kernel<<<dim3(TOKENS), dim3(256), 0, stream>>>(out, pairs, pairpos);
}